// Round 12
// baseline (42.636 us; speedup 1.0000x reference)
//
#include <hip/hip_runtime.h>

constexpr int B = 8, N = 1024, FIN = 128, FOUT = 64, H = 4;
constexpr float LOG2E = 1.44269504f;

typedef __attribute__((ext_vector_type(8))) short short8;
typedef __attribute__((ext_vector_type(4))) short short4v;
typedef __attribute__((ext_vector_type(4))) float f32x4;

// f32 -> bf16 round-to-nearest-even (prep-kernel use only)
static __device__ inline unsigned short f2bf(float x) {
    union { float f; unsigned u; } v; v.f = x;
    unsigned r = v.u + 0x7fff + ((v.u >> 16) & 1);
    return (unsigned short)(r >> 16);
}

// ---------------------------------------------------------------------------
// Fused prep kernel. Blocks 0..511: mbB (A-fragment-order bf16 masked bias).
// Blocks 512..2559: h_prime GEMM + ei/ej. 4-row blocks, K split 4-ways across
// lane groups (kh = lane>>4), combined via shfl_xor(16)+shfl_xor(32):
// 32 serial iters/thread (was 64), grid 2048 -> 8 waves/SIMD.
//   mbB[ti][jc][lane][e] bf16 = (i=ti*16+(lane&15), j=jc*32+8*(lane>>4)+e)
//   hpF[bh][jc][ft][lane][e] bf16 = hp(f=ft*16+(lane&15), n=jc*32+8*(lane>>4)+e)
// ---------------------------------------------------------------------------
__global__ __launch_bounds__(256) void gat_prep(
    const float* __restrict__ h,      // (B,N,FIN)
    const float* __restrict__ W,      // (H,FIN,FOUT)
    const float* __restrict__ a,      // (H,2*FOUT,1)
    const int*   __restrict__ adj,    // (N,N)
    const float* __restrict__ bias,   // (N,N)
    unsigned short* __restrict__ hpF, // fragment-order bf16 (4 MB)
    unsigned short* __restrict__ mbB, // fragment-order bf16 (2 MB)
    float* __restrict__ ei_t,         // (B,H,N) *LOG2E
    float* __restrict__ ej_t)         // (B,H,N) *LOG2E
{
    __shared__ float h_lds[4][132];
    const int t = threadIdx.x;

    if (blockIdx.x < 512) {           // ---- mb part (R11-verified) ----
        const int bx   = blockIdx.x;
        const int ti   = bx >> 3;
        const int jc   = (bx & 7) * 4 + (t >> 6);
        const int lane = t & 63;
        const int i    = ti * 16 + (lane & 15);
        const int j0   = jc * 32 + 8 * (lane >> 4);

        const int4*   ap = reinterpret_cast<const int4*>(adj + (size_t)i * N + j0);
        const float4* bp = reinterpret_cast<const float4*>(bias + (size_t)i * N + j0);
        int4   a0 = ap[0], a1 = ap[1];
        float4 b0 = bp[0], b1 = bp[1];
        unsigned short q0 = f2bf(a0.x ? LOG2E * b0.x : -1e35f);
        unsigned short q1 = f2bf(a0.y ? LOG2E * b0.y : -1e35f);
        unsigned short q2 = f2bf(a0.z ? LOG2E * b0.z : -1e35f);
        unsigned short q3 = f2bf(a0.w ? LOG2E * b0.w : -1e35f);
        unsigned short q4 = f2bf(a1.x ? LOG2E * b1.x : -1e35f);
        unsigned short q5 = f2bf(a1.y ? LOG2E * b1.y : -1e35f);
        unsigned short q6 = f2bf(a1.z ? LOG2E * b1.z : -1e35f);
        unsigned short q7 = f2bf(a1.w ? LOG2E * b1.w : -1e35f);
        int4 ov;
        ov.x = (int)((unsigned)q0 | ((unsigned)q1 << 16));
        ov.y = (int)((unsigned)q2 | ((unsigned)q3 << 16));
        ov.z = (int)((unsigned)q4 | ((unsigned)q5 << 16));
        ov.w = (int)((unsigned)q6 | ((unsigned)q7 << 16));
        *reinterpret_cast<int4*>(mbB + (((size_t)ti * 32 + jc) * 64 + lane) * 8) = ov;
        return;
    }

    // ---- h_prime part: 4 rows, K/4 per lane group ----
    const int blk = blockIdx.x - 512;       // 0..2047
    const int b   = blk >> 8;                // / (N/4)
    const int n0  = (blk & 255) * 4;

    if (t < 128) {                           // stage 4 x 128 floats (2KB)
        const float* src = h + ((size_t)b * N + n0) * FIN;
        float4 x = reinterpret_cast<const float4*>(src)[t];
        int fl = t * 4;
        *reinterpret_cast<float4*>(&h_lds[fl >> 7][fl & 127]) = x;
    }
    __syncthreads();

    const int hd   = t >> 6;
    const int lane = t & 63;
    const int li   = lane & 15;
    const int f0   = li * 4;
    const int kh   = lane >> 4;              // K quarter

    float acc[4][4];                          // [row][f]
    #pragma unroll
    for (int k = 0; k < 4; ++k)
        #pragma unroll
        for (int j = 0; j < 4; ++j) acc[k][j] = 0.f;

    const float* Wp = W + (size_t)hd * FIN * FOUT + (size_t)kh * 32 * FOUT + f0;
    #pragma unroll 4
    for (int i = 0; i < 32; ++i) {
        float4 w4 = *reinterpret_cast<const float4*>(Wp + (size_t)i * FOUT);
        #pragma unroll
        for (int k = 0; k < 4; ++k) {
            float hv = h_lds[k][kh * 32 + i];
            acc[k][0] = fmaf(hv, w4.x, acc[k][0]);
            acc[k][1] = fmaf(hv, w4.y, acc[k][1]);
            acc[k][2] = fmaf(hv, w4.z, acc[k][2]);
            acc[k][3] = fmaf(hv, w4.w, acc[k][3]);
        }
    }

    // combine the 4 K-quarters (all lanes end with the full sum)
    #pragma unroll
    for (int k = 0; k < 4; ++k)
        #pragma unroll
        for (int j = 0; j < 4; ++j) {
            acc[k][j] += __shfl_xor(acc[k][j], 16, 64);
            acc[k][j] += __shfl_xor(acc[k][j], 32, 64);
        }

    const int bh = b * H + hd;
    if (kh == 0) {
        // rows n0..n0+3 (n0 % 4 == 0), f = f0+jj. Frag coords:
        //   jc = n0>>5, kg_n = (n0>>3)&3, e = (n0&4)+k, lane' = 4*(li&3)+jj + 16*kg_n
        const int jc  = n0 >> 5;
        const int kgn = (n0 >> 3) & 3;
        const int ft  = li >> 2;
        const int e0  = n0 & 4;
        #pragma unroll
        for (int jj = 0; jj < 4; ++jj) {
            short4v v4;
            v4[0] = (short)f2bf(acc[0][jj]);
            v4[1] = (short)f2bf(acc[1][jj]);
            v4[2] = (short)f2bf(acc[2][jj]);
            v4[3] = (short)f2bf(acc[3][jj]);
            const int lanep = (4 * (li & 3) + jj) + 16 * kgn;
            *reinterpret_cast<short4v*>(
                hpF + ((((size_t)bh * 32 + jc) * 4 + ft) * 64 + lanep) * 8 + e0) = v4;
        }
    }

    float4 a1 = *reinterpret_cast<const float4*>(a + (size_t)hd * 2 * FOUT + f0);
    float4 a2 = *reinterpret_cast<const float4*>(a + (size_t)hd * 2 * FOUT + FOUT + f0);
    #pragma unroll
    for (int k = 0; k < 4; ++k) {
        float e1 = acc[k][0] * a1.x + acc[k][1] * a1.y + acc[k][2] * a1.z + acc[k][3] * a1.w;
        float e2 = acc[k][0] * a2.x + acc[k][1] * a2.y + acc[k][2] * a2.z + acc[k][3] * a2.w;
        #pragma unroll
        for (int m = 1; m < 16; m <<= 1) {
            e1 += __shfl_xor(e1, m, 64);
            e2 += __shfl_xor(e2, m, 64);
        }
        if (lane == 0) {                      // li==0 && kh==0
            int r = n0 + k;
            ei_t[(size_t)bh * N + r] = LOG2E * e1;
            ej_t[(size_t)bh * N + r] = LOG2E * e2;
        }
    }
}

// ---------------------------------------------------------------------------
// Kernel B: fused scores+softmax+PV. 512 threads = 8 waves = (i-tile w, j-half
// jh). T3/T4 pipeline: 3 rotating LDS hpF buffers, STAGE issued 2 chunks
// ahead, counted `s_waitcnt vmcnt(4)` + raw s_barrier (never drain-0 in the
// loop). Ledger per phase: issue {STAGE(c+2), mq(c+1), ejA(c+1), ejB(c+1)}
// = 4 outstanding allowed; FIFO => STAGE(c+1) & older retired at the barrier.
// Tail phases clamp the prefetch index (re-stage into a never-read buffer).
// ---------------------------------------------------------------------------
__global__ __launch_bounds__(512) void gat_attn(
    const unsigned short* __restrict__ hpF, // fragment-order bf16
    const float* __restrict__ ei_t,         // (B,H,N) *LOG2E
    const float* __restrict__ ej_t,         // (B,H,N) *LOG2E
    const unsigned short* __restrict__ mbB, // fragment-order bf16 masked bias
    float* __restrict__ out)                // (B,N,H*FOUT)
{
    __shared__ __align__(16) unsigned short hstage[3][2][4][512]; // 24KB
    __shared__ f32x4 red[5][4][64];                               // 20KB
    const int raw  = blockIdx.x;            // 512
    const int xcd  = raw & 7;
    const int k_   = raw >> 3;
    const int bh   = ((xcd >> 1) << 3) | (k_ >> 3);          // 8 bh per XCD
    const int it0  = (((xcd & 1) << 3) | (k_ & 7)) * 4;      // 4 i-tiles/block
    const int t    = threadIdx.x;
    const int w8   = t >> 6;
    const int w    = w8 & 3;                // i-tile (also f-tile staged)
    const int jh   = w8 >> 2;               // j-half
    const int lane = t & 63;
    const int li   = lane & 15;
    const int kg   = lane >> 4;
    const int ti   = it0 + w;
    const int irow = ti * 16 + li;
    const int jcb  = jh * 16;               // first chunk of this wave's half

    const float  ei0   = ei_t[(size_t)bh * N + irow];
    const float* ejrow = ej_t + (size_t)bh * N;
    const unsigned short* mrow = mbB + ((size_t)ti * 32 * 64 + lane) * 8;  // + jc*512
    const size_t hbase = (size_t)bh * 65536;                               // u16/slab

    f32x4 c0 = {0.f,0.f,0.f,0.f}, c1 = {0.f,0.f,0.f,0.f};
    f32x4 c2 = {0.f,0.f,0.f,0.f}, c3 = {0.f,0.f,0.f,0.f};
    f32x4 c4 = {0.f,0.f,0.f,0.f};
    const short obf = (short)0x3F80;                      // bf16 1.0
    const short8 ones = {obf,obf,obf,obf,obf,obf,obf,obf};

    #define VMCNT4() asm volatile("s_waitcnt vmcnt(4)" ::: "memory")
    #define BARRIER() { __builtin_amdgcn_s_barrier(); asm volatile("" ::: "memory"); }

    // stage f-tile w of chunk JCG into hstage[BUF][jh][w]
    #define STAGE(BUF, JCG) {                                                 \
        const unsigned short* gs_ = hpF + hbase + (size_t)(JCG) * 2048        \
                                        + (size_t)w * 512 + (size_t)lane * 8; \
        __builtin_amdgcn_global_load_lds(                                     \
            (const __attribute__((address_space(1))) void*)gs_,               \
            (__attribute__((address_space(3))) void*)&hstage[BUF][jh][w][0],  \
            16, 0, 0); }

    // register prefetch for chunk JCG into set S (mq + 2 ej float4s)
    #define REGS(S, JCG) {                                                    \
        mq##S  = *reinterpret_cast<const int4*>(mrow + (size_t)(JCG) * 512);  \
        ejA##S = *reinterpret_cast<const float4*>(ejrow + (JCG) * 32 + 8 * kg);\
        ejB##S = *reinterpret_cast<const float4*>(ejrow + (JCG) * 32 + 8 * kg + 4); }

    #define DSREAD(BUF, BA, BB, BC, BD) {                                     \
        BA = *reinterpret_cast<const short8*>(&hstage[BUF][jh][0][lane * 8]); \
        BB = *reinterpret_cast<const short8*>(&hstage[BUF][jh][1][lane * 8]); \
        BC = *reinterpret_cast<const short8*>(&hstage[BUF][jh][2][lane * 8]); \
        BD = *reinterpret_cast<const short8*>(&hstage[BUF][jh][3][lane * 8]); }

    // two scores from one packed-bf16 word (lo = even elem, hi = odd elem)
    #define SCORE2(PL, PH, EJL, EJH, QW) {                                    \
        float bl_ = __uint_as_float(((unsigned)(QW)) << 16);                  \
        float bh_ = __uint_as_float(((unsigned)(QW)) & 0xffff0000u);          \
        float el_ = ei0 + (EJL); el_ = fmaxf(el_, 0.2f * el_) + bl_;          \
        float eh_ = ei0 + (EJH); eh_ = fmaxf(eh_, 0.2f * eh_) + bh_;          \
        asm("v_exp_f32 %0, %1" : "=v"(PL) : "v"(el_));                        \
        asm("v_exp_f32 %0, %1" : "=v"(PH) : "v"(eh_)); }

    #define COMPS(S, BA, BB, BC, BD) {                                        \
        float p0,p1,p2,p3,p4,p5,p6,p7;                                        \
        SCORE2(p0, p1, ejA##S.x, ejA##S.y, mq##S.x)                           \
        SCORE2(p2, p3, ejA##S.z, ejA##S.w, mq##S.y)                           \
        SCORE2(p4, p5, ejB##S.x, ejB##S.y, mq##S.z)                           \
        SCORE2(p6, p7, ejB##S.z, ejB##S.w, mq##S.w)                           \
        int4 pk_;                                                             \
        asm("v_cvt_pk_bf16_f32 %0, %1, %2" : "=v"(pk_.x) : "v"(p0), "v"(p1)); \
        asm("v_cvt_pk_bf16_f32 %0, %1, %2" : "=v"(pk_.y) : "v"(p2), "v"(p3)); \
        asm("v_cvt_pk_bf16_f32 %0, %1, %2" : "=v"(pk_.z) : "v"(p4), "v"(p5)); \
        asm("v_cvt_pk_bf16_f32 %0, %1, %2" : "=v"(pk_.w) : "v"(p6), "v"(p7)); \
        short8 a0_ = *reinterpret_cast<short8*>(&pk_);                        \
        c0 = __builtin_amdgcn_mfma_f32_16x16x32_bf16(a0_, BA, c0, 0, 0, 0);   \
        c1 = __builtin_amdgcn_mfma_f32_16x16x32_bf16(a0_, BB, c1, 0, 0, 0);   \
        c2 = __builtin_amdgcn_mfma_f32_16x16x32_bf16(a0_, BC, c2, 0, 0, 0);   \
        c3 = __builtin_amdgcn_mfma_f32_16x16x32_bf16(a0_, BD, c3, 0, 0, 0);   \
        c4 = __builtin_amdgcn_mfma_f32_16x16x32_bf16(a0_, ones, c4, 0, 0, 0); }

    short8 A0, B0, C0, D0, A1, B1, C1, D1;
    int4 mq0, mq1;
    float4 ejA0, ejB0, ejA1, ejB1;

    // prologue: stage chunks 0,1; regs for chunk 0.
    STAGE(0, jcb + 0)
    STAGE(1, jcb + 1)
    REGS(0, jcb + 0)
    VMCNT4();                                // S0 retired; S1+regs0... (<=4 left)
    BARRIER();                               // all waves' S0 landed

    int ba = 0, bb = 1;                      // LDS buf of chunk k, k+1 (k%3)
    #pragma unroll 1
    for (int k = 0; k < 16; k += 2) {
        const int p2 = (k + 2 < 16) ? jcb + k + 2 : jcb + 15;   // clamped prefetch
        const int p3 = (k + 3 < 16) ? jcb + k + 3 : jcb + 15;
        const int bn0 = ba == 0 ? 2 : (ba == 1 ? 0 : 1);        // (ba+2)%3
        const int bn1 = bb == 0 ? 2 : (bb == 1 ? 0 : 1);        // (bb+2)%3
        // --- phase A: chunk jcb+k from buf ba ---
        STAGE(bn0, p2)
        REGS(1, jcb + k + 1)
        DSREAD(ba, A0, B0, C0, D0)
        COMPS(0, A0, B0, C0, D0)
        VMCNT4();                            // S(k+1) & older retired
        BARRIER();
        // --- phase B: chunk jcb+k+1 from buf bb ---
        STAGE(bn1, p3)
        REGS(0, p2)
        DSREAD(bb, A1, B1, C1, D1)
        COMPS(1, A1, B1, C1, D1)
        VMCNT4();                            // S(k+2) & older retired
        BARRIER();
        ba = bn0; bb = bn1;
    }
    #undef VMCNT4
    #undef BARRIER
    #undef STAGE
    #undef REGS
    #undef DSREAD
    #undef SCORE2
    #undef COMPS

    // combine j-halves: jh==1 dumps partials, jh==0 adds + finishes.
    if (jh == 1) {
        red[0][w][lane] = c0;
        red[1][w][lane] = c1;
        red[2][w][lane] = c2;
        red[3][w][lane] = c3;
        red[4][w][lane] = c4;
    }
    __syncthreads();
    if (jh == 1) return;

    c0 += red[0][w][lane];
    c1 += red[1][w][lane];
    c2 += red[2][w][lane];
    c3 += red[3][w][lane];
    c4 += red[4][w][lane];

    // C layout col=li (f within tile), row=4*kg+r; c4[r] = that row's sum.
    const int b  = bh >> 2;
    const int hd = bh & 3;
    #pragma unroll
    for (int r = 0; r < 4; ++r) {
        int orow = ti * 16 + 4 * kg + r;
        float inv = 1.0f / c4[r];
        float* ob = out + (((size_t)b * N + orow) * H + hd) * 64 + li;
        ob[0]  = c0[r] * inv;
        ob[16] = c1[r] * inv;
        ob[32] = c2[r] * inv;
        ob[48] = c3[r] * inv;
    }
}

extern "C" void kernel_launch(void* const* d_in, const int* in_sizes, int n_in,
                              void* d_out, int out_size, void* d_ws, size_t ws_size,
                              hipStream_t stream) {
    const float* h    = (const float*)d_in[0];
    const int*   adj  = (const int*)  d_in[1];
    const float* bias = (const float*)d_in[2];
    const float* W    = (const float*)d_in[3];
    const float* a    = (const float*)d_in[4];
    float* out = (float*)d_out;

    char* ws = (char*)d_ws;
    unsigned short* hpF = (unsigned short*)ws;                        // 4 MB
    unsigned short* mbB = (unsigned short*)(ws + ((size_t)4 << 20));  // 2 MB
    float* ei_t = (float*)(ws + ((size_t)6 << 20));                   // 128 KB
    float* ej_t = ei_t + (size_t)B * H * N;                           // 128 KB

    gat_prep<<<512 + B * N / 4, 256, 0, stream>>>(h, W, a, adj, bias,
                                                  hpF, mbB, ei_t, ej_t);
    gat_attn<<<B * H * (N / 64), 512, 0, stream>>>(hpF, ei_t, ej_t, mbB, out);
}

// Round 13
// 37.531 us; speedup vs baseline: 1.1360x; 1.1360x over previous
//
#include <hip/hip_runtime.h>

constexpr int B = 8, N = 1024, FIN = 128, FOUT = 64, H = 4;
constexpr float LOG2E = 1.44269504f;

typedef __attribute__((ext_vector_type(8))) short short8;
typedef __attribute__((ext_vector_type(4))) short short4v;
typedef __attribute__((ext_vector_type(4))) float f32x4;

// f32 -> bf16 round-to-nearest-even (prep-kernel use only)
static __device__ inline unsigned short f2bf(float x) {
    union { float f; unsigned u; } v; v.f = x;
    unsigned r = v.u + 0x7fff + ((v.u >> 16) & 1);
    return (unsigned short)(r >> 16);
}

// ---------------------------------------------------------------------------
// Fused prep kernel. Blocks 0..511: mbB (A-fragment-order bf16 masked bias,
// R11-verified verbatim). Blocks 512..1023: h_prime GEMM + ei/ej, 16-row
// blocks, FULL K per thread (max W reuse: W traffic halved vs R11; no
// cross-lane K reduce). Thread = (head hd, f-quad f0, row-group rg of 4).
//   mbB[ti][jc][lane][e] bf16 = (i=ti*16+(lane&15), j=jc*32+8*(lane>>4)+e)
//   hpF[bh][jc][ft][lane][e] bf16 = hp(f=ft*16+(lane&15), n=jc*32+8*(lane>>4)+e)
// ---------------------------------------------------------------------------
__global__ __launch_bounds__(256) void gat_prep(
    const float* __restrict__ h,      // (B,N,FIN)
    const float* __restrict__ W,      // (H,FIN,FOUT)
    const float* __restrict__ a,      // (H,2*FOUT,1)
    const int*   __restrict__ adj,    // (N,N)
    const float* __restrict__ bias,   // (N,N)
    unsigned short* __restrict__ hpF, // fragment-order bf16 (4 MB)
    unsigned short* __restrict__ mbB, // fragment-order bf16 (2 MB)
    float* __restrict__ ei_t,         // (B,H,N) *LOG2E
    float* __restrict__ ej_t)         // (B,H,N) *LOG2E
{
    __shared__ float h_lds[16][132];
    const int t = threadIdx.x;

    if (blockIdx.x < 512) {           // ---- mb part (R11-verified) ----
        const int bx   = blockIdx.x;
        const int ti   = bx >> 3;
        const int jc   = (bx & 7) * 4 + (t >> 6);
        const int lane = t & 63;
        const int i    = ti * 16 + (lane & 15);
        const int j0   = jc * 32 + 8 * (lane >> 4);

        const int4*   ap = reinterpret_cast<const int4*>(adj + (size_t)i * N + j0);
        const float4* bp = reinterpret_cast<const float4*>(bias + (size_t)i * N + j0);
        int4   a0 = ap[0], a1 = ap[1];
        float4 b0 = bp[0], b1 = bp[1];
        unsigned short q0 = f2bf(a0.x ? LOG2E * b0.x : -1e35f);
        unsigned short q1 = f2bf(a0.y ? LOG2E * b0.y : -1e35f);
        unsigned short q2 = f2bf(a0.z ? LOG2E * b0.z : -1e35f);
        unsigned short q3 = f2bf(a0.w ? LOG2E * b0.w : -1e35f);
        unsigned short q4 = f2bf(a1.x ? LOG2E * b1.x : -1e35f);
        unsigned short q5 = f2bf(a1.y ? LOG2E * b1.y : -1e35f);
        unsigned short q6 = f2bf(a1.z ? LOG2E * b1.z : -1e35f);
        unsigned short q7 = f2bf(a1.w ? LOG2E * b1.w : -1e35f);
        int4 ov;
        ov.x = (int)((unsigned)q0 | ((unsigned)q1 << 16));
        ov.y = (int)((unsigned)q2 | ((unsigned)q3 << 16));
        ov.z = (int)((unsigned)q4 | ((unsigned)q5 << 16));
        ov.w = (int)((unsigned)q6 | ((unsigned)q7 << 16));
        *reinterpret_cast<int4*>(mbB + (((size_t)ti * 32 + jc) * 64 + lane) * 8) = ov;
        return;
    }

    // ---- h_prime part: 16 rows, full K per thread ----
    const int blk = blockIdx.x - 512;        // 0..511
    const int b   = blk >> 6;                // / (N/16)
    const int n0  = (blk & 63) * 16;

    {   // stage 16 rows x 128 f32 (8KB): 512 float4, 2 per thread
        const float* src = h + ((size_t)b * N + n0) * FIN;
        for (int v = t; v < 512; v += 256) {
            float4 x = reinterpret_cast<const float4*>(src)[v];
            int fl = v * 4;
            *reinterpret_cast<float4*>(&h_lds[fl >> 7][fl & 127]) = x;
        }
    }
    __syncthreads();

    const int hd   = t >> 6;
    const int lane = t & 63;
    const int li   = lane & 15;              // f-quad index
    const int f0   = li * 4;
    const int rg   = lane >> 4;              // rows 4*rg .. 4*rg+3

    float acc[4][4];                         // [k][jj]: row n0+4rg+k, f f0+jj
    #pragma unroll
    for (int k = 0; k < 4; ++k)
        #pragma unroll
        for (int j = 0; j < 4; ++j) acc[k][j] = 0.f;

    const float* Wp = W + (size_t)hd * FIN * FOUT + f0;
    #pragma unroll 8
    for (int i = 0; i < FIN; ++i) {
        float4 w4 = *reinterpret_cast<const float4*>(Wp + (size_t)i * FOUT);
        #pragma unroll
        for (int k = 0; k < 4; ++k) {
            float hv = h_lds[4 * rg + k][i];
            acc[k][0] = fmaf(hv, w4.x, acc[k][0]);
            acc[k][1] = fmaf(hv, w4.y, acc[k][1]);
            acc[k][2] = fmaf(hv, w4.z, acc[k][2]);
            acc[k][3] = fmaf(hv, w4.w, acc[k][3]);
        }
    }

    const int bh = b * H + hd;
    // hpF store for rows na..na+3 (na = n0+4rg, same jc for all rg):
    //   kgn = (na>>3)&3, e0 = na&4, lane' = 4*(li&3)+jj + 16*kgn, ft = li>>2
    {
        const int na  = n0 + 4 * rg;
        const int jc  = na >> 5;
        const int kgn = (na >> 3) & 3;
        const int ft  = li >> 2;
        const int e0  = na & 4;
        #pragma unroll
        for (int jj = 0; jj < 4; ++jj) {
            short4v v4;
            v4[0] = (short)f2bf(acc[0][jj]);
            v4[1] = (short)f2bf(acc[1][jj]);
            v4[2] = (short)f2bf(acc[2][jj]);
            v4[3] = (short)f2bf(acc[3][jj]);
            const int lanep = (4 * (li & 3) + jj) + 16 * kgn;
            *reinterpret_cast<short4v*>(
                hpF + ((((size_t)bh * 32 + jc) * 4 + ft) * 64 + lanep) * 8 + e0) = v4;
        }
    }

    // ei/ej: dot with a1/a2, butterfly over the 16 f-quad lanes of this rg
    float4 a1 = *reinterpret_cast<const float4*>(a + (size_t)hd * 2 * FOUT + f0);
    float4 a2 = *reinterpret_cast<const float4*>(a + (size_t)hd * 2 * FOUT + FOUT + f0);
    #pragma unroll
    for (int k = 0; k < 4; ++k) {
        float e1 = acc[k][0] * a1.x + acc[k][1] * a1.y + acc[k][2] * a1.z + acc[k][3] * a1.w;
        float e2 = acc[k][0] * a2.x + acc[k][1] * a2.y + acc[k][2] * a2.z + acc[k][3] * a2.w;
        #pragma unroll
        for (int m = 1; m < 16; m <<= 1) {
            e1 += __shfl_xor(e1, m, 64);
            e2 += __shfl_xor(e2, m, 64);
        }
        // butterfly leaves the group sum on every lane; one writer per rg group
        if (li == 0) {
            int r = n0 + 4 * rg + k;
            ei_t[(size_t)bh * N + r] = LOG2E * e1;
            ej_t[(size_t)bh * N + r] = LOG2E * e2;
        }
    }
}

// ---------------------------------------------------------------------------
// Kernel B: fused scores+softmax+PV (R11-verified 38.1µs version, verbatim).
// 512 threads = 8 waves = (i-tile w, j-half jh); hpF LDS-staged via
// global_load_lds, double-buffered, one barrier per chunk; bf16 mbB;
// c4 ones-MFMA row sums -> register-local normalization.
// ---------------------------------------------------------------------------
__global__ __launch_bounds__(512) void gat_attn(
    const unsigned short* __restrict__ hpF, // fragment-order bf16
    const float* __restrict__ ei_t,         // (B,H,N) *LOG2E
    const float* __restrict__ ej_t,         // (B,H,N) *LOG2E
    const unsigned short* __restrict__ mbB, // fragment-order bf16 masked bias
    float* __restrict__ out)                // (B,N,H*FOUT)
{
    __shared__ __align__(16) unsigned short hstage[2][2][4][512]; // 16KB [buf][jh][ft][lane*8+e]
    __shared__ f32x4 red[5][4][64];                               // 20KB
    const int raw  = blockIdx.x;            // 512
    const int xcd  = raw & 7;
    const int k_   = raw >> 3;
    const int bh   = ((xcd >> 1) << 3) | (k_ >> 3);          // 8 bh per XCD
    const int it0  = (((xcd & 1) << 3) | (k_ & 7)) * 4;      // 4 i-tiles/block
    const int t    = threadIdx.x;
    const int w8   = t >> 6;
    const int w    = w8 & 3;                // i-tile (also: f-tile this wave stages)
    const int jh   = w8 >> 2;               // j-half
    const int lane = t & 63;
    const int li   = lane & 15;
    const int kg   = lane >> 4;
    const int ti   = it0 + w;
    const int irow = ti * 16 + li;
    const int jcb  = jh * 16;               // first chunk of this wave's half

    const float  ei0   = ei_t[(size_t)bh * N + irow];
    const float* ejrow = ej_t + (size_t)bh * N;
    const unsigned short* mrow = mbB + ((size_t)ti * 32 * 64 + lane) * 8;  // + jc*512
    const size_t hbase = (size_t)bh * 65536;                               // u16/slab

    f32x4 c0 = {0.f,0.f,0.f,0.f}, c1 = {0.f,0.f,0.f,0.f};
    f32x4 c2 = {0.f,0.f,0.f,0.f}, c3 = {0.f,0.f,0.f,0.f};
    f32x4 c4 = {0.f,0.f,0.f,0.f};
    const short obf = (short)0x3F80;                      // bf16 1.0
    const short8 ones = {obf,obf,obf,obf,obf,obf,obf,obf};

    // stage f-tile w of chunk JCG into hstage[BUF][jh][w]
    #define STAGE(BUF, JCG) {                                                 \
        const unsigned short* gs_ = hpF + hbase + (size_t)(JCG) * 2048        \
                                        + (size_t)w * 512 + (size_t)lane * 8; \
        __builtin_amdgcn_global_load_lds(                                     \
            (const __attribute__((address_space(1))) void*)gs_,               \
            (__attribute__((address_space(3))) void*)&hstage[BUF][jh][w][0],  \
            16, 0, 0); }

    #define DSREAD(BUF, BA, BB, BC, BD) {                                     \
        BA = *reinterpret_cast<const short8*>(&hstage[BUF][jh][0][lane * 8]); \
        BB = *reinterpret_cast<const short8*>(&hstage[BUF][jh][1][lane * 8]); \
        BC = *reinterpret_cast<const short8*>(&hstage[BUF][jh][2][lane * 8]); \
        BD = *reinterpret_cast<const short8*>(&hstage[BUF][jh][3][lane * 8]); }

    // two scores from one packed-bf16 word (lo = even elem, hi = odd elem)
    #define SCORE2(PL, PH, EJL, EJH, QW) {                                    \
        float bl_ = __uint_as_float(((unsigned)(QW)) << 16);                  \
        float bh_ = __uint_as_float(((unsigned)(QW)) & 0xffff0000u);          \
        float el_ = ei0 + (EJL); el_ = fmaxf(el_, 0.2f * el_) + bl_;          \
        float eh_ = ei0 + (EJH); eh_ = fmaxf(eh_, 0.2f * eh_) + bh_;          \
        asm("v_exp_f32 %0, %1" : "=v"(PL) : "v"(el_));                        \
        asm("v_exp_f32 %0, %1" : "=v"(PH) : "v"(eh_)); }

    #define COMPS(MQ, BA, BB, BC, BD, JC) {                                   \
        float4 ejA = *reinterpret_cast<const float4*>(ejrow + (JC) * 32 + 8 * kg);     \
        float4 ejB = *reinterpret_cast<const float4*>(ejrow + (JC) * 32 + 8 * kg + 4); \
        float p0,p1,p2,p3,p4,p5,p6,p7;                                        \
        SCORE2(p0, p1, ejA.x, ejA.y, MQ.x)                                    \
        SCORE2(p2, p3, ejA.z, ejA.w, MQ.y)                                    \
        SCORE2(p4, p5, ejB.x, ejB.y, MQ.z)                                    \
        SCORE2(p6, p7, ejB.z, ejB.w, MQ.w)                                    \
        int4 pk_;                                                             \
        asm("v_cvt_pk_bf16_f32 %0, %1, %2" : "=v"(pk_.x) : "v"(p0), "v"(p1)); \
        asm("v_cvt_pk_bf16_f32 %0, %1, %2" : "=v"(pk_.y) : "v"(p2), "v"(p3)); \
        asm("v_cvt_pk_bf16_f32 %0, %1, %2" : "=v"(pk_.z) : "v"(p4), "v"(p5)); \
        asm("v_cvt_pk_bf16_f32 %0, %1, %2" : "=v"(pk_.w) : "v"(p6), "v"(p7)); \
        short8 a0_ = *reinterpret_cast<short8*>(&pk_);                        \
        c0 = __builtin_amdgcn_mfma_f32_16x16x32_bf16(a0_, BA, c0, 0, 0, 0);   \
        c1 = __builtin_amdgcn_mfma_f32_16x16x32_bf16(a0_, BB, c1, 0, 0, 0);   \
        c2 = __builtin_amdgcn_mfma_f32_16x16x32_bf16(a0_, BC, c2, 0, 0, 0);   \
        c3 = __builtin_amdgcn_mfma_f32_16x16x32_bf16(a0_, BD, c3, 0, 0, 0);   \
        c4 = __builtin_amdgcn_mfma_f32_16x16x32_bf16(a0_, ones, c4, 0, 0, 0); }

    short8 A0, B0, C0, D0, A1, B1, C1, D1;
    int4 mq0, mq1;

    STAGE(0, jcb)
    mq0 = *reinterpret_cast<const int4*>(mrow + (size_t)jcb * 512);
    __syncthreads();                         // stage(0) visible

    for (int jc = 0; jc < 16; jc += 2) {
        // --- half A: consume buf0/mq0, prefetch buf1/mq1 ---
        STAGE(1, jcb + jc + 1)
        mq1 = *reinterpret_cast<const int4*>(mrow + (size_t)(jcb + jc + 1) * 512);
        DSREAD(0, A0, B0, C0, D0)
        COMPS(mq0, A0, B0, C0, D0, jcb + jc)
        __syncthreads();                     // stage(1) visible; buf0 free
        // --- half B: consume buf1/mq1, prefetch buf0/mq0 ---
        if (jc + 2 < 16) {
            STAGE(0, jcb + jc + 2)
            mq0 = *reinterpret_cast<const int4*>(mrow + (size_t)(jcb + jc + 2) * 512);
        }
        DSREAD(1, A1, B1, C1, D1)
        COMPS(mq1, A1, B1, C1, D1, jcb + jc + 1)
        __syncthreads();                     // stage(0) visible; buf1 free
    }
    #undef STAGE
    #undef DSREAD
    #undef SCORE2
    #undef COMPS

    // combine j-halves: jh==1 dumps partials, jh==0 adds + finishes.
    if (jh == 1) {
        red[0][w][lane] = c0;
        red[1][w][lane] = c1;
        red[2][w][lane] = c2;
        red[3][w][lane] = c3;
        red[4][w][lane] = c4;
    }
    __syncthreads();
    if (jh == 1) return;

    c0 += red[0][w][lane];
    c1 += red[1][w][lane];
    c2 += red[2][w][lane];
    c3 += red[3][w][lane];
    c4 += red[4][w][lane];

    // C layout col=li (f within tile), row=4*kg+r; c4[r] = that row's sum.
    const int b  = bh >> 2;
    const int hd = bh & 3;
    #pragma unroll
    for (int r = 0; r < 4; ++r) {
        int orow = ti * 16 + 4 * kg + r;
        float inv = 1.0f / c4[r];
        float* ob = out + (((size_t)b * N + orow) * H + hd) * 64 + li;
        ob[0]  = c0[r] * inv;
        ob[16] = c1[r] * inv;
        ob[32] = c2[r] * inv;
        ob[48] = c3[r] * inv;
    }
}

extern "C" void kernel_launch(void* const* d_in, const int* in_sizes, int n_in,
                              void* d_out, int out_size, void* d_ws, size_t ws_size,
                              hipStream_t stream) {
    const float* h    = (const float*)d_in[0];
    const int*   adj  = (const int*)  d_in[1];
    const float* bias = (const float*)d_in[2];
    const float* W    = (const float*)d_in[3];
    const float* a    = (const float*)d_in[4];
    float* out = (float*)d_out;

    char* ws = (char*)d_ws;
    unsigned short* hpF = (unsigned short*)ws;                        // 4 MB
    unsigned short* mbB = (unsigned short*)(ws + ((size_t)4 << 20));  // 2 MB
    float* ei_t = (float*)(ws + ((size_t)6 << 20));                   // 128 KB
    float* ej_t = ei_t + (size_t)B * H * N;                           // 128 KB

    gat_prep<<<512 + B * N / 16, 256, 0, stream>>>(h, W, a, adj, bias,
                                                   hpF, mbB, ei_t, ej_t);
    gat_attn<<<B * H * (N / 64), 512, 0, stream>>>(hpF, ei_t, ej_t, mbB, out);
}

// Round 14
// 35.799 us; speedup vs baseline: 1.1910x; 1.0484x over previous
//
#include <hip/hip_runtime.h>

constexpr int B = 8, N = 1024, FIN = 128, FOUT = 64, H = 4;
constexpr float LOG2E = 1.44269504f;

typedef __attribute__((ext_vector_type(8))) short short8;
typedef __attribute__((ext_vector_type(4))) short short4v;
typedef __attribute__((ext_vector_type(4))) float f32x4;

// f32 -> bf16 round-to-nearest-even (prep-kernel use only)
static __device__ inline unsigned short f2bf(float x) {
    union { float f; unsigned u; } v; v.f = x;
    unsigned r = v.u + 0x7fff + ((v.u >> 16) & 1);
    return (unsigned short)(r >> 16);
}

// ---------------------------------------------------------------------------
// Fused prep kernel — R13-verified VERBATIM (control variable this round).
// Blocks 0..511: mbB. Blocks 512..1023: h_prime 16-row full-K + ei/ej.
// ---------------------------------------------------------------------------
__global__ __launch_bounds__(256) void gat_prep(
    const float* __restrict__ h,      // (B,N,FIN)
    const float* __restrict__ W,      // (H,FIN,FOUT)
    const float* __restrict__ a,      // (H,2*FOUT,1)
    const int*   __restrict__ adj,    // (N,N)
    const float* __restrict__ bias,   // (N,N)
    unsigned short* __restrict__ hpF, // fragment-order bf16 (4 MB)
    unsigned short* __restrict__ mbB, // fragment-order bf16 (2 MB)
    float* __restrict__ ei_t,         // (B,H,N) *LOG2E
    float* __restrict__ ej_t)         // (B,H,N) *LOG2E
{
    __shared__ float h_lds[16][132];
    const int t = threadIdx.x;

    if (blockIdx.x < 512) {           // ---- mb part (R11-verified) ----
        const int bx   = blockIdx.x;
        const int ti   = bx >> 3;
        const int jc   = (bx & 7) * 4 + (t >> 6);
        const int lane = t & 63;
        const int i    = ti * 16 + (lane & 15);
        const int j0   = jc * 32 + 8 * (lane >> 4);

        const int4*   ap = reinterpret_cast<const int4*>(adj + (size_t)i * N + j0);
        const float4* bp = reinterpret_cast<const float4*>(bias + (size_t)i * N + j0);
        int4   a0 = ap[0], a1 = ap[1];
        float4 b0 = bp[0], b1 = bp[1];
        unsigned short q0 = f2bf(a0.x ? LOG2E * b0.x : -1e35f);
        unsigned short q1 = f2bf(a0.y ? LOG2E * b0.y : -1e35f);
        unsigned short q2 = f2bf(a0.z ? LOG2E * b0.z : -1e35f);
        unsigned short q3 = f2bf(a0.w ? LOG2E * b0.w : -1e35f);
        unsigned short q4 = f2bf(a1.x ? LOG2E * b1.x : -1e35f);
        unsigned short q5 = f2bf(a1.y ? LOG2E * b1.y : -1e35f);
        unsigned short q6 = f2bf(a1.z ? LOG2E * b1.z : -1e35f);
        unsigned short q7 = f2bf(a1.w ? LOG2E * b1.w : -1e35f);
        int4 ov;
        ov.x = (int)((unsigned)q0 | ((unsigned)q1 << 16));
        ov.y = (int)((unsigned)q2 | ((unsigned)q3 << 16));
        ov.z = (int)((unsigned)q4 | ((unsigned)q5 << 16));
        ov.w = (int)((unsigned)q6 | ((unsigned)q7 << 16));
        *reinterpret_cast<int4*>(mbB + (((size_t)ti * 32 + jc) * 64 + lane) * 8) = ov;
        return;
    }

    // ---- h_prime part: 16 rows, full K per thread ----
    const int blk = blockIdx.x - 512;        // 0..511
    const int b   = blk >> 6;                // / (N/16)
    const int n0  = (blk & 63) * 16;

    {   // stage 16 rows x 128 f32 (8KB): 512 float4, 2 per thread
        const float* src = h + ((size_t)b * N + n0) * FIN;
        for (int v = t; v < 512; v += 256) {
            float4 x = reinterpret_cast<const float4*>(src)[v];
            int fl = v * 4;
            *reinterpret_cast<float4*>(&h_lds[fl >> 7][fl & 127]) = x;
        }
    }
    __syncthreads();

    const int hd   = t >> 6;
    const int lane = t & 63;
    const int li   = lane & 15;              // f-quad index
    const int f0   = li * 4;
    const int rg   = lane >> 4;              // rows 4*rg .. 4*rg+3

    float acc[4][4];                         // [k][jj]: row n0+4rg+k, f f0+jj
    #pragma unroll
    for (int k = 0; k < 4; ++k)
        #pragma unroll
        for (int j = 0; j < 4; ++j) acc[k][j] = 0.f;

    const float* Wp = W + (size_t)hd * FIN * FOUT + f0;
    #pragma unroll 8
    for (int i = 0; i < FIN; ++i) {
        float4 w4 = *reinterpret_cast<const float4*>(Wp + (size_t)i * FOUT);
        #pragma unroll
        for (int k = 0; k < 4; ++k) {
            float hv = h_lds[4 * rg + k][i];
            acc[k][0] = fmaf(hv, w4.x, acc[k][0]);
            acc[k][1] = fmaf(hv, w4.y, acc[k][1]);
            acc[k][2] = fmaf(hv, w4.z, acc[k][2]);
            acc[k][3] = fmaf(hv, w4.w, acc[k][3]);
        }
    }

    const int bh = b * H + hd;
    {
        const int na  = n0 + 4 * rg;
        const int jc  = na >> 5;
        const int kgn = (na >> 3) & 3;
        const int ft  = li >> 2;
        const int e0  = na & 4;
        #pragma unroll
        for (int jj = 0; jj < 4; ++jj) {
            short4v v4;
            v4[0] = (short)f2bf(acc[0][jj]);
            v4[1] = (short)f2bf(acc[1][jj]);
            v4[2] = (short)f2bf(acc[2][jj]);
            v4[3] = (short)f2bf(acc[3][jj]);
            const int lanep = (4 * (li & 3) + jj) + 16 * kgn;
            *reinterpret_cast<short4v*>(
                hpF + ((((size_t)bh * 32 + jc) * 4 + ft) * 64 + lanep) * 8 + e0) = v4;
        }
    }

    float4 a1 = *reinterpret_cast<const float4*>(a + (size_t)hd * 2 * FOUT + f0);
    float4 a2 = *reinterpret_cast<const float4*>(a + (size_t)hd * 2 * FOUT + FOUT + f0);
    #pragma unroll
    for (int k = 0; k < 4; ++k) {
        float e1 = acc[k][0] * a1.x + acc[k][1] * a1.y + acc[k][2] * a1.z + acc[k][3] * a1.w;
        float e2 = acc[k][0] * a2.x + acc[k][1] * a2.y + acc[k][2] * a2.z + acc[k][3] * a2.w;
        #pragma unroll
        for (int m = 1; m < 16; m <<= 1) {
            e1 += __shfl_xor(e1, m, 64);
            e2 += __shfl_xor(e2, m, 64);
        }
        if (li == 0) {
            int r = n0 + 4 * rg + k;
            ei_t[(size_t)bh * N + r] = LOG2E * e1;
            ej_t[(size_t)bh * N + r] = LOG2E * e2;
        }
    }
}

// ---------------------------------------------------------------------------
// Kernel B: fused scores+softmax+PV. R12-verified 3-buffer counted-vmcnt
// pipeline (T3/T4), with the R12 occupancy bug fixed: the 20KB `red` reduce
// buffer is ALIASED over the 24KB hstage region (hstage is dead after the
// main loop) -> total LDS 24KB (was 44KB in R12, 36KB in R11/R13).
// Ledger per phase: issue {STAGE(c+2), mq(c+1), ejA(c+1), ejB(c+1)} = 4;
// `s_waitcnt vmcnt(4)` at phase end => STAGE(c+1) & older retired; the
// just-issued REGS are NOT drained (that drain was R11/R13's per-phase stall).
// ---------------------------------------------------------------------------
__global__ __launch_bounds__(512) void gat_attn(
    const unsigned short* __restrict__ hpF, // fragment-order bf16
    const float* __restrict__ ei_t,         // (B,H,N) *LOG2E
    const float* __restrict__ ej_t,         // (B,H,N) *LOG2E
    const unsigned short* __restrict__ mbB, // fragment-order bf16 masked bias
    float* __restrict__ out)                // (B,N,H*FOUT)
{
    __shared__ __align__(16) char smem[24576];   // hstage[3][2][4][512] u16; red aliased after loop
    typedef unsigned short hstage_t[2][4][512];
    hstage_t* hstage = reinterpret_cast<hstage_t*>(smem);

    const int raw  = blockIdx.x;            // 512
    const int xcd  = raw & 7;
    const int k_   = raw >> 3;
    const int bh   = ((xcd >> 1) << 3) | (k_ >> 3);          // 8 bh per XCD
    const int it0  = (((xcd & 1) << 3) | (k_ & 7)) * 4;      // 4 i-tiles/block
    const int t    = threadIdx.x;
    const int w8   = t >> 6;
    const int w    = w8 & 3;                // i-tile (also f-tile staged)
    const int jh   = w8 >> 2;               // j-half
    const int lane = t & 63;
    const int li   = lane & 15;
    const int kg   = lane >> 4;
    const int ti   = it0 + w;
    const int irow = ti * 16 + li;
    const int jcb  = jh * 16;               // first chunk of this wave's half

    const float  ei0   = ei_t[(size_t)bh * N + irow];
    const float* ejrow = ej_t + (size_t)bh * N;
    const unsigned short* mrow = mbB + ((size_t)ti * 32 * 64 + lane) * 8;  // + jc*512
    const size_t hbase = (size_t)bh * 65536;                               // u16/slab

    f32x4 c0 = {0.f,0.f,0.f,0.f}, c1 = {0.f,0.f,0.f,0.f};
    f32x4 c2 = {0.f,0.f,0.f,0.f}, c3 = {0.f,0.f,0.f,0.f};
    f32x4 c4 = {0.f,0.f,0.f,0.f};
    const short obf = (short)0x3F80;                      // bf16 1.0
    const short8 ones = {obf,obf,obf,obf,obf,obf,obf,obf};

    #define VMCNT4() asm volatile("s_waitcnt vmcnt(4)" ::: "memory")
    #define BARRIER() { __builtin_amdgcn_s_barrier(); asm volatile("" ::: "memory"); }

    // stage f-tile w of chunk JCG into hstage[BUF][jh][w]
    #define STAGE(BUF, JCG) {                                                 \
        const unsigned short* gs_ = hpF + hbase + (size_t)(JCG) * 2048        \
                                        + (size_t)w * 512 + (size_t)lane * 8; \
        __builtin_amdgcn_global_load_lds(                                     \
            (const __attribute__((address_space(1))) void*)gs_,               \
            (__attribute__((address_space(3))) void*)&hstage[BUF][jh][w][0],  \
            16, 0, 0); }

    // register prefetch for chunk JCG into set S (mq + 2 ej float4s)
    #define REGS(S, JCG) {                                                    \
        mq##S  = *reinterpret_cast<const int4*>(mrow + (size_t)(JCG) * 512);  \
        ejA##S = *reinterpret_cast<const float4*>(ejrow + (JCG) * 32 + 8 * kg);\
        ejB##S = *reinterpret_cast<const float4*>(ejrow + (JCG) * 32 + 8 * kg + 4); }

    #define DSREAD(BUF, BA, BB, BC, BD) {                                     \
        BA = *reinterpret_cast<const short8*>(&hstage[BUF][jh][0][lane * 8]); \
        BB = *reinterpret_cast<const short8*>(&hstage[BUF][jh][1][lane * 8]); \
        BC = *reinterpret_cast<const short8*>(&hstage[BUF][jh][2][lane * 8]); \
        BD = *reinterpret_cast<const short8*>(&hstage[BUF][jh][3][lane * 8]); }

    // two scores from one packed-bf16 word (lo = even elem, hi = odd elem)
    #define SCORE2(PL, PH, EJL, EJH, QW) {                                    \
        float bl_ = __uint_as_float(((unsigned)(QW)) << 16);                  \
        float bh_ = __uint_as_float(((unsigned)(QW)) & 0xffff0000u);          \
        float el_ = ei0 + (EJL); el_ = fmaxf(el_, 0.2f * el_) + bl_;          \
        float eh_ = ei0 + (EJH); eh_ = fmaxf(eh_, 0.2f * eh_) + bh_;          \
        asm("v_exp_f32 %0, %1" : "=v"(PL) : "v"(el_));                        \
        asm("v_exp_f32 %0, %1" : "=v"(PH) : "v"(eh_)); }

    #define COMPS(S, BA, BB, BC, BD) {                                        \
        float p0,p1,p2,p3,p4,p5,p6,p7;                                        \
        SCORE2(p0, p1, ejA##S.x, ejA##S.y, mq##S.x)                           \
        SCORE2(p2, p3, ejA##S.z, ejA##S.w, mq##S.y)                           \
        SCORE2(p4, p5, ejB##S.x, ejB##S.y, mq##S.z)                           \
        SCORE2(p6, p7, ejB##S.z, ejB##S.w, mq##S.w)                           \
        int4 pk_;                                                             \
        asm("v_cvt_pk_bf16_f32 %0, %1, %2" : "=v"(pk_.x) : "v"(p0), "v"(p1)); \
        asm("v_cvt_pk_bf16_f32 %0, %1, %2" : "=v"(pk_.y) : "v"(p2), "v"(p3)); \
        asm("v_cvt_pk_bf16_f32 %0, %1, %2" : "=v"(pk_.z) : "v"(p4), "v"(p5)); \
        asm("v_cvt_pk_bf16_f32 %0, %1, %2" : "=v"(pk_.w) : "v"(p6), "v"(p7)); \
        short8 a0_ = *reinterpret_cast<short8*>(&pk_);                        \
        c0 = __builtin_amdgcn_mfma_f32_16x16x32_bf16(a0_, BA, c0, 0, 0, 0);   \
        c1 = __builtin_amdgcn_mfma_f32_16x16x32_bf16(a0_, BB, c1, 0, 0, 0);   \
        c2 = __builtin_amdgcn_mfma_f32_16x16x32_bf16(a0_, BC, c2, 0, 0, 0);   \
        c3 = __builtin_amdgcn_mfma_f32_16x16x32_bf16(a0_, BD, c3, 0, 0, 0);   \
        c4 = __builtin_amdgcn_mfma_f32_16x16x32_bf16(a0_, ones, c4, 0, 0, 0); }

    short8 A0, B0, C0, D0, A1, B1, C1, D1;
    int4 mq0, mq1;
    float4 ejA0, ejB0, ejA1, ejB1;

    // prologue: stage chunks 0,1; regs for chunk 0.
    STAGE(0, jcb + 0)
    STAGE(1, jcb + 1)
    REGS(0, jcb + 0)
    VMCNT4();                                // S0 retired (<=4 outstanding)
    BARRIER();                               // all waves' S0 landed

    int ba = 0, bb = 1;                      // LDS buf of chunk k, k+1 (k%3)
    #pragma unroll 1
    for (int k = 0; k < 16; k += 2) {
        const int p2 = (k + 2 < 16) ? jcb + k + 2 : jcb + 15;   // clamped prefetch
        const int p3 = (k + 3 < 16) ? jcb + k + 3 : jcb + 15;
        const int bn0 = ba == 0 ? 2 : (ba == 1 ? 0 : 1);        // (ba+2)%3
        const int bn1 = bb == 0 ? 2 : (bb == 1 ? 0 : 1);        // (bb+2)%3
        // --- phase A: chunk jcb+k from buf ba ---
        STAGE(bn0, p2)
        REGS(1, jcb + k + 1)
        DSREAD(ba, A0, B0, C0, D0)
        COMPS(0, A0, B0, C0, D0)
        VMCNT4();                            // S(k+1) & older retired
        BARRIER();
        // --- phase B: chunk jcb+k+1 from buf bb ---
        STAGE(bn1, p3)
        REGS(0, p2)
        DSREAD(bb, A1, B1, C1, D1)
        COMPS(1, A1, B1, C1, D1)
        VMCNT4();                            // S(k+2) & older retired
        BARRIER();
        ba = bn0; bb = bn1;
    }
    #undef VMCNT4
    #undef BARRIER
    #undef STAGE
    #undef REGS
    #undef DSREAD
    #undef SCORE2
    #undef COMPS

    // hstage is dead from here on: alias the reduce buffer over it (saves 20KB)
    f32x4 (*red)[4][64] = reinterpret_cast<f32x4 (*)[4][64]>(smem);

    // combine j-halves: jh==1 dumps partials, jh==0 adds + finishes.
    __syncthreads();                         // everyone past final DSREAD
    if (jh == 1) {
        red[0][w][lane] = c0;
        red[1][w][lane] = c1;
        red[2][w][lane] = c2;
        red[3][w][lane] = c3;
        red[4][w][lane] = c4;
    }
    __syncthreads();
    if (jh == 1) return;

    c0 += red[0][w][lane];
    c1 += red[1][w][lane];
    c2 += red[2][w][lane];
    c3 += red[3][w][lane];
    c4 += red[4][w][lane];

    // C layout col=li (f within tile), row=4*kg+r; c4[r] = that row's sum.
    const int b  = bh >> 2;
    const int hd = bh & 3;
    #pragma unroll
    for (int r = 0; r < 4; ++r) {
        int orow = ti * 16 + 4 * kg + r;
        float inv = 1.0f / c4[r];
        float* ob = out + (((size_t)b * N + orow) * H + hd) * 64 + li;
        ob[0]  = c0[r] * inv;
        ob[16] = c1[r] * inv;
        ob[32] = c2[r] * inv;
        ob[48] = c3[r] * inv;
    }
}

extern "C" void kernel_launch(void* const* d_in, const int* in_sizes, int n_in,
                              void* d_out, int out_size, void* d_ws, size_t ws_size,
                              hipStream_t stream) {
    const float* h    = (const float*)d_in[0];
    const int*   adj  = (const int*)  d_in[1];
    const float* bias = (const float*)d_in[2];
    const float* W    = (const float*)d_in[3];
    const float* a    = (const float*)d_in[4];
    float* out = (float*)d_out;

    char* ws = (char*)d_ws;
    unsigned short* hpF = (unsigned short*)ws;                        // 4 MB
    unsigned short* mbB = (unsigned short*)(ws + ((size_t)4 << 20));  // 2 MB
    float* ei_t = (float*)(ws + ((size_t)6 << 20));                   // 128 KB
    float* ej_t = ei_t + (size_t)B * H * N;                           // 128 KB

    gat_prep<<<512 + B * N / 16, 256, 0, stream>>>(h, W, a, adj, bias,
                                                   hpF, mbB, ei_t, ej_t);
    gat_attn<<<B * H * (N / 64), 512, 0, stream>>>(hpF, ei_t, ej_t, mbB, out);
}

// Round 17
// 35.236 us; speedup vs baseline: 1.2100x; 1.0160x over previous
//
#include <hip/hip_runtime.h>

constexpr int B = 8, N = 1024, FIN = 128, FOUT = 64, H = 4;
constexpr float LOG2E = 1.44269504f;

typedef __attribute__((ext_vector_type(8))) short short8;
typedef __attribute__((ext_vector_type(4))) short short4v;
typedef __attribute__((ext_vector_type(4))) float f32x4;

// f32 -> bf16 round-to-nearest-even (prep-kernel use only)
static __device__ inline unsigned short f2bf(float x) {
    union { float f; unsigned u; } v; v.f = x;
    unsigned r = v.u + 0x7fff + ((v.u >> 16) & 1);
    return (unsigned short)(r >> 16);
}

// ---------------------------------------------------------------------------
// Fused prep kernel — R13-verified VERBATIM.
// Blocks 0..511: mbB. Blocks 512..1023: h_prime 16-row full-K + ei/ej.
// ---------------------------------------------------------------------------
__global__ __launch_bounds__(256) void gat_prep(
    const float* __restrict__ h,      // (B,N,FIN)
    const float* __restrict__ W,      // (H,FIN,FOUT)
    const float* __restrict__ a,      // (H,2*FOUT,1)
    const int*   __restrict__ adj,    // (N,N)
    const float* __restrict__ bias,   // (N,N)
    unsigned short* __restrict__ hpF, // fragment-order bf16 (4 MB)
    unsigned short* __restrict__ mbB, // fragment-order bf16 (2 MB)
    float* __restrict__ ei_t,         // (B,H,N) *LOG2E
    float* __restrict__ ej_t)         // (B,H,N) *LOG2E
{
    __shared__ float h_lds[16][132];
    const int t = threadIdx.x;

    if (blockIdx.x < 512) {           // ---- mb part (R11-verified) ----
        const int bx   = blockIdx.x;
        const int ti   = bx >> 3;
        const int jc   = (bx & 7) * 4 + (t >> 6);
        const int lane = t & 63;
        const int i    = ti * 16 + (lane & 15);
        const int j0   = jc * 32 + 8 * (lane >> 4);

        const int4*   ap = reinterpret_cast<const int4*>(adj + (size_t)i * N + j0);
        const float4* bp = reinterpret_cast<const float4*>(bias + (size_t)i * N + j0);
        int4   a0 = ap[0], a1 = ap[1];
        float4 b0 = bp[0], b1 = bp[1];
        unsigned short q0 = f2bf(a0.x ? LOG2E * b0.x : -1e35f);
        unsigned short q1 = f2bf(a0.y ? LOG2E * b0.y : -1e35f);
        unsigned short q2 = f2bf(a0.z ? LOG2E * b0.z : -1e35f);
        unsigned short q3 = f2bf(a0.w ? LOG2E * b0.w : -1e35f);
        unsigned short q4 = f2bf(a1.x ? LOG2E * b1.x : -1e35f);
        unsigned short q5 = f2bf(a1.y ? LOG2E * b1.y : -1e35f);
        unsigned short q6 = f2bf(a1.z ? LOG2E * b1.z : -1e35f);
        unsigned short q7 = f2bf(a1.w ? LOG2E * b1.w : -1e35f);
        int4 ov;
        ov.x = (int)((unsigned)q0 | ((unsigned)q1 << 16));
        ov.y = (int)((unsigned)q2 | ((unsigned)q3 << 16));
        ov.z = (int)((unsigned)q4 | ((unsigned)q5 << 16));
        ov.w = (int)((unsigned)q6 | ((unsigned)q7 << 16));
        *reinterpret_cast<int4*>(mbB + (((size_t)ti * 32 + jc) * 64 + lane) * 8) = ov;
        return;
    }

    // ---- h_prime part: 16 rows, full K per thread ----
    const int blk = blockIdx.x - 512;        // 0..511
    const int b   = blk >> 6;                // / (N/16)
    const int n0  = (blk & 63) * 16;

    {   // stage 16 rows x 128 f32 (8KB): 512 float4, 2 per thread
        const float* src = h + ((size_t)b * N + n0) * FIN;
        for (int v = t; v < 512; v += 256) {
            float4 x = reinterpret_cast<const float4*>(src)[v];
            int fl = v * 4;
            *reinterpret_cast<float4*>(&h_lds[fl >> 7][fl & 127]) = x;
        }
    }
    __syncthreads();

    const int hd   = t >> 6;
    const int lane = t & 63;
    const int li   = lane & 15;              // f-quad index
    const int f0   = li * 4;
    const int rg   = lane >> 4;              // rows 4*rg .. 4*rg+3

    float acc[4][4];                         // [k][jj]: row n0+4rg+k, f f0+jj
    #pragma unroll
    for (int k = 0; k < 4; ++k)
        #pragma unroll
        for (int j = 0; j < 4; ++j) acc[k][j] = 0.f;

    const float* Wp = W + (size_t)hd * FIN * FOUT + f0;
    #pragma unroll 8
    for (int i = 0; i < FIN; ++i) {
        float4 w4 = *reinterpret_cast<const float4*>(Wp + (size_t)i * FOUT);
        #pragma unroll
        for (int k = 0; k < 4; ++k) {
            float hv = h_lds[4 * rg + k][i];
            acc[k][0] = fmaf(hv, w4.x, acc[k][0]);
            acc[k][1] = fmaf(hv, w4.y, acc[k][1]);
            acc[k][2] = fmaf(hv, w4.z, acc[k][2]);
            acc[k][3] = fmaf(hv, w4.w, acc[k][3]);
        }
    }

    const int bh = b * H + hd;
    {
        const int na  = n0 + 4 * rg;
        const int jc  = na >> 5;
        const int kgn = (na >> 3) & 3;
        const int ft  = li >> 2;
        const int e0  = na & 4;
        #pragma unroll
        for (int jj = 0; jj < 4; ++jj) {
            short4v v4;
            v4[0] = (short)f2bf(acc[0][jj]);
            v4[1] = (short)f2bf(acc[1][jj]);
            v4[2] = (short)f2bf(acc[2][jj]);
            v4[3] = (short)f2bf(acc[3][jj]);
            const int lanep = (4 * (li & 3) + jj) + 16 * kgn;
            *reinterpret_cast<short4v*>(
                hpF + ((((size_t)bh * 32 + jc) * 4 + ft) * 64 + lanep) * 8 + e0) = v4;
        }
    }

    float4 a1 = *reinterpret_cast<const float4*>(a + (size_t)hd * 2 * FOUT + f0);
    float4 a2 = *reinterpret_cast<const float4*>(a + (size_t)hd * 2 * FOUT + FOUT + f0);
    #pragma unroll
    for (int k = 0; k < 4; ++k) {
        float e1 = acc[k][0] * a1.x + acc[k][1] * a1.y + acc[k][2] * a1.z + acc[k][3] * a1.w;
        float e2 = acc[k][0] * a2.x + acc[k][1] * a2.y + acc[k][2] * a2.z + acc[k][3] * a2.w;
        #pragma unroll
        for (int m = 1; m < 16; m <<= 1) {
            e1 += __shfl_xor(e1, m, 64);
            e2 += __shfl_xor(e2, m, 64);
        }
        if (li == 0) {
            int r = n0 + 4 * rg + k;
            ei_t[(size_t)bh * N + r] = LOG2E * e1;
            ej_t[(size_t)bh * N + r] = LOG2E * e2;
        }
    }
}

// ---------------------------------------------------------------------------
// Kernel B: fused scores+softmax+PV. Merged 2-chunk phases, quad-buffer,
// barriers 33 -> 17.
// R15/R16 BUG (found): each stage buffer is [jh=2][ft=4][512 u16] = 8KB,
// so 4 buffers = 32KB — but smem was declared 20480B. Buffers 2,3 were OUT
// OF BOUNDS -> deterministic garbage (identical absmax both rounds).
// Fix: smem[32768]. vmcnt(6) ledger stands: phase queue (oldest->newest)
// [STAGE x2, REGS(0) x3, REGS(1) x3]; <=6 retires exactly the 2 STAGEs the
// next phase consumes; just-issued REGS stay in flight.
// ---------------------------------------------------------------------------
__global__ __launch_bounds__(512) void gat_attn(
    const unsigned short* __restrict__ hpF, // fragment-order bf16
    const float* __restrict__ ei_t,         // (B,H,N) *LOG2E
    const float* __restrict__ ej_t,         // (B,H,N) *LOG2E
    const unsigned short* __restrict__ mbB, // fragment-order bf16 masked bias
    float* __restrict__ out)                // (B,N,H*FOUT)
{
    __shared__ __align__(16) char smem[32768];   // hstage[4] x 8KB; red (20KB) aliased after loop
    typedef unsigned short hstage_t[2][4][512];
    hstage_t* hstage = reinterpret_cast<hstage_t*>(smem);

    const int raw  = blockIdx.x;            // 512
    const int xcd  = raw & 7;
    const int k_   = raw >> 3;
    const int bh   = ((xcd >> 1) << 3) | (k_ >> 3);          // 8 bh per XCD
    const int it0  = (((xcd & 1) << 3) | (k_ & 7)) * 4;      // 4 i-tiles/block
    const int t    = threadIdx.x;
    const int w8   = t >> 6;
    const int w    = w8 & 3;                // i-tile (also f-tile staged)
    const int jh   = w8 >> 2;               // j-half
    const int lane = t & 63;
    const int li   = lane & 15;
    const int kg   = lane >> 4;
    const int ti   = it0 + w;
    const int irow = ti * 16 + li;
    const int jcb  = jh * 16;               // first chunk of this wave's half

    const float  ei0   = ei_t[(size_t)bh * N + irow];
    const float* ejrow = ej_t + (size_t)bh * N;
    const unsigned short* mrow = mbB + ((size_t)ti * 32 * 64 + lane) * 8;  // + jc*512
    const size_t hbase = (size_t)bh * 65536;                               // u16/slab

    f32x4 c0 = {0.f,0.f,0.f,0.f}, c1 = {0.f,0.f,0.f,0.f};
    f32x4 c2 = {0.f,0.f,0.f,0.f}, c3 = {0.f,0.f,0.f,0.f};
    f32x4 c4 = {0.f,0.f,0.f,0.f};
    const short obf = (short)0x3F80;                      // bf16 1.0
    const short8 ones = {obf,obf,obf,obf,obf,obf,obf,obf};

    #define VMCNT6() asm volatile("s_waitcnt vmcnt(6)" ::: "memory")
    #define BARRIER() { __builtin_amdgcn_s_barrier(); asm volatile("" ::: "memory"); }

    // stage f-tile w of chunk JCG into hstage[BUF][jh][w]
    #define STAGE(BUF, JCG) {                                                 \
        const unsigned short* gs_ = hpF + hbase + (size_t)(JCG) * 2048        \
                                        + (size_t)w * 512 + (size_t)lane * 8; \
        __builtin_amdgcn_global_load_lds(                                     \
            (const __attribute__((address_space(1))) void*)gs_,               \
            (__attribute__((address_space(3))) void*)&hstage[BUF][jh][w][0],  \
            16, 0, 0); }

    // register prefetch for chunk JCG into set S (mq + 2 ej float4s)
    #define REGS(S, JCG) {                                                    \
        mq##S  = *reinterpret_cast<const int4*>(mrow + (size_t)(JCG) * 512);  \
        ejA##S = *reinterpret_cast<const float4*>(ejrow + (JCG) * 32 + 8 * kg);\
        ejB##S = *reinterpret_cast<const float4*>(ejrow + (JCG) * 32 + 8 * kg + 4); }

    #define DSREAD(BUF, BA, BB, BC, BD) {                                     \
        BA = *reinterpret_cast<const short8*>(&hstage[BUF][jh][0][lane * 8]); \
        BB = *reinterpret_cast<const short8*>(&hstage[BUF][jh][1][lane * 8]); \
        BC = *reinterpret_cast<const short8*>(&hstage[BUF][jh][2][lane * 8]); \
        BD = *reinterpret_cast<const short8*>(&hstage[BUF][jh][3][lane * 8]); }

    // two scores from one packed-bf16 word (lo = even elem, hi = odd elem)
    #define SCORE2(PL, PH, EJL, EJH, QW) {                                    \
        float bl_ = __uint_as_float(((unsigned)(QW)) << 16);                  \
        float bh_ = __uint_as_float(((unsigned)(QW)) & 0xffff0000u);          \
        float el_ = ei0 + (EJL); el_ = fmaxf(el_, 0.2f * el_) + bl_;          \
        float eh_ = ei0 + (EJH); eh_ = fmaxf(eh_, 0.2f * eh_) + bh_;          \
        asm("v_exp_f32 %0, %1" : "=v"(PL) : "v"(el_));                        \
        asm("v_exp_f32 %0, %1" : "=v"(PH) : "v"(eh_)); }

    #define COMPS(S, BA, BB, BC, BD) {                                        \
        float p0,p1,p2,p3,p4,p5,p6,p7;                                        \
        SCORE2(p0, p1, ejA##S.x, ejA##S.y, mq##S.x)                           \
        SCORE2(p2, p3, ejA##S.z, ejA##S.w, mq##S.y)                           \
        SCORE2(p4, p5, ejB##S.x, ejB##S.y, mq##S.z)                           \
        SCORE2(p6, p7, ejB##S.z, ejB##S.w, mq##S.w)                           \
        int4 pk_;                                                             \
        asm("v_cvt_pk_bf16_f32 %0, %1, %2" : "=v"(pk_.x) : "v"(p0), "v"(p1)); \
        asm("v_cvt_pk_bf16_f32 %0, %1, %2" : "=v"(pk_.y) : "v"(p2), "v"(p3)); \
        asm("v_cvt_pk_bf16_f32 %0, %1, %2" : "=v"(pk_.z) : "v"(p4), "v"(p5)); \
        asm("v_cvt_pk_bf16_f32 %0, %1, %2" : "=v"(pk_.w) : "v"(p6), "v"(p7)); \
        short8 a0_ = *reinterpret_cast<short8*>(&pk_);                        \
        c0 = __builtin_amdgcn_mfma_f32_16x16x32_bf16(a0_, BA, c0, 0, 0, 0);   \
        c1 = __builtin_amdgcn_mfma_f32_16x16x32_bf16(a0_, BB, c1, 0, 0, 0);   \
        c2 = __builtin_amdgcn_mfma_f32_16x16x32_bf16(a0_, BC, c2, 0, 0, 0);   \
        c3 = __builtin_amdgcn_mfma_f32_16x16x32_bf16(a0_, BD, c3, 0, 0, 0);   \
        c4 = __builtin_amdgcn_mfma_f32_16x16x32_bf16(a0_, ones, c4, 0, 0, 0); }

    short8 A0, B0, C0, D0, A1, B1, C1, D1;
    int4 mq0, mq1;
    float4 ejA0, ejB0, ejA1, ejB1;

    // prologue: stage chunks 0,1 (buf 0,1); regs for chunks 0,1.
    STAGE(0, jcb + 0)
    STAGE(1, jcb + 1)
    REGS(0, jcb + 0)
    REGS(1, jcb + 1)
    VMCNT6();                                // both STAGEs retired
    BARRIER();

    // 8 merged phases; phase k consumes chunks k,k+1 from bufs k%4,(k+1)%4
    // and stages chunks k+2,k+3 into bufs (k+2)%4,(k+3)%4.
    #pragma unroll 1
    for (int k = 0; k < 16; k += 2) {
        const int pa = (k + 2 < 16) ? jcb + k + 2 : jcb + 15;   // clamped prefetch
        const int pb = (k + 3 < 16) ? jcb + k + 3 : jcb + 15;
        const int ba = k & 2 ? 2 : 0;        // k%4 (k even)
        const int bb = ba + 1;               // (k+1)%4
        const int bn0 = ba ^ 2;              // (k+2)%4
        const int bn1 = bb ^ 2;              // (k+3)%4
        // issue next-phase stages up front
        STAGE(bn0, pa)
        STAGE(bn1, pb)
        // consume chunk k
        DSREAD(ba, A0, B0, C0, D0)
        COMPS(0, A0, B0, C0, D0)
        REGS(0, pa)
        // consume chunk k+1
        DSREAD(bb, A1, B1, C1, D1)
        COMPS(1, A1, B1, C1, D1)
        REGS(1, pb)
        VMCNT6();                            // retires this phase's 2 STAGEs (oldest)
        BARRIER();
    }
    #undef VMCNT6
    #undef BARRIER
    #undef STAGE
    #undef REGS
    #undef DSREAD
    #undef SCORE2
    #undef COMPS

    // hstage is dead from here on: alias the reduce buffer over it
    f32x4 (*red)[4][64] = reinterpret_cast<f32x4 (*)[4][64]>(smem);

    __syncthreads();                         // everyone past final DSREAD
    if (jh == 1) {
        red[0][w][lane] = c0;
        red[1][w][lane] = c1;
        red[2][w][lane] = c2;
        red[3][w][lane] = c3;
        red[4][w][lane] = c4;
    }
    __syncthreads();
    if (jh == 1) return;

    c0 += red[0][w][lane];
    c1 += red[1][w][lane];
    c2 += red[2][w][lane];
    c3 += red[3][w][lane];
    c4 += red[4][w][lane];

    // C layout col=li (f within tile), row=4*kg+r; c4[r] = that row's sum.
    const int b  = bh >> 2;
    const int hd = bh & 3;
    #pragma unroll
    for (int r = 0; r < 4; ++r) {
        int orow = ti * 16 + 4 * kg + r;
        float inv = 1.0f / c4[r];
        float* ob = out + (((size_t)b * N + orow) * H + hd) * 64 + li;
        ob[0]  = c0[r] * inv;
        ob[16] = c1[r] * inv;
        ob[32] = c2[r] * inv;
        ob[48] = c3[r] * inv;
    }
}

extern "C" void kernel_launch(void* const* d_in, const int* in_sizes, int n_in,
                              void* d_out, int out_size, void* d_ws, size_t ws_size,
                              hipStream_t stream) {
    const float* h    = (const float*)d_in[0];
    const int*   adj  = (const int*)  d_in[1];
    const float* bias = (const float*)d_in[2];
    const float* W    = (const float*)d_in[3];
    const float* a    = (const float*)d_in[4];
    float* out = (float*)d_out;

    char* ws = (char*)d_ws;
    unsigned short* hpF = (unsigned short*)ws;                        // 4 MB
    unsigned short* mbB = (unsigned short*)(ws + ((size_t)4 << 20));  // 2 MB
    float* ei_t = (float*)(ws + ((size_t)6 << 20));                   // 128 KB
    float* ej_t = ei_t + (size_t)B * H * N;                           // 128 KB

    gat_prep<<<512 + B * N / 16, 256, 0, stream>>>(h, W, a, adj, bias,
                                                   hpF, mbB, ei_t, ej_t);
    gat_attn<<<B * H * (N / 64), 512, 0, stream>>>(hpF, ei_t, ej_t, mbB, out);
}

// Round 18
// 34.713 us; speedup vs baseline: 1.2282x; 1.0151x over previous
//
#include <hip/hip_runtime.h>

constexpr int B = 8, N = 1024, FIN = 128, FOUT = 64, H = 4;
constexpr float LOG2E = 1.44269504f;

typedef __attribute__((ext_vector_type(8))) short short8;
typedef __attribute__((ext_vector_type(4))) short short4v;
typedef __attribute__((ext_vector_type(4))) float f32x4;

// f32 -> bf16 round-to-nearest-even (prep-kernel use only)
static __device__ inline unsigned short f2bf(float x) {
    union { float f; unsigned u; } v; v.f = x;
    unsigned r = v.u + 0x7fff + ((v.u >> 16) & 1);
    return (unsigned short)(r >> 16);
}

// ---------------------------------------------------------------------------
// Fused prep kernel. Blocks 0..511: mbB (R11-verified verbatim).
// Blocks 512..767: h_prime GEMM on MFMA + ei/ej.
//   Block = (b, 32 rows); wave = head. h staged in LDS (pad+4 -> 2-way only).
//   W pre-built into 16 B-fragments per wave (k-bijection k=ks*32+8*kg+e,
//   same convention as the verified attn MFMAs). 32 MFMAs replace 2048
//   FMA/thread. C layout (row=4kg+r, col=li) -> same verified hpF store
//   formula with lanep = li + 16*(2rt+(kg>>1)), e0 = 4*(kg&1).
// ---------------------------------------------------------------------------
__global__ __launch_bounds__(256) void gat_prep(
    const float* __restrict__ h,      // (B,N,FIN)
    const float* __restrict__ W,      // (H,FIN,FOUT)
    const float* __restrict__ a,      // (H,2*FOUT,1)
    const int*   __restrict__ adj,    // (N,N)
    const float* __restrict__ bias,   // (N,N)
    unsigned short* __restrict__ hpF, // fragment-order bf16 (4 MB)
    unsigned short* __restrict__ mbB, // fragment-order bf16 (2 MB)
    float* __restrict__ ei_t,         // (B,H,N) *LOG2E
    float* __restrict__ ej_t)         // (B,H,N) *LOG2E
{
    __shared__ float h_lds[32][132];
    const int t = threadIdx.x;

    if (blockIdx.x < 512) {           // ---- mb part (R11-verified) ----
        const int bx   = blockIdx.x;
        const int ti   = bx >> 3;
        const int jc   = (bx & 7) * 4 + (t >> 6);
        const int lane = t & 63;
        const int i    = ti * 16 + (lane & 15);
        const int j0   = jc * 32 + 8 * (lane >> 4);

        const int4*   ap = reinterpret_cast<const int4*>(adj + (size_t)i * N + j0);
        const float4* bp = reinterpret_cast<const float4*>(bias + (size_t)i * N + j0);
        int4   a0 = ap[0], a1 = ap[1];
        float4 b0 = bp[0], b1 = bp[1];
        unsigned short q0 = f2bf(a0.x ? LOG2E * b0.x : -1e35f);
        unsigned short q1 = f2bf(a0.y ? LOG2E * b0.y : -1e35f);
        unsigned short q2 = f2bf(a0.z ? LOG2E * b0.z : -1e35f);
        unsigned short q3 = f2bf(a0.w ? LOG2E * b0.w : -1e35f);
        unsigned short q4 = f2bf(a1.x ? LOG2E * b1.x : -1e35f);
        unsigned short q5 = f2bf(a1.y ? LOG2E * b1.y : -1e35f);
        unsigned short q6 = f2bf(a1.z ? LOG2E * b1.z : -1e35f);
        unsigned short q7 = f2bf(a1.w ? LOG2E * b1.w : -1e35f);
        int4 ov;
        ov.x = (int)((unsigned)q0 | ((unsigned)q1 << 16));
        ov.y = (int)((unsigned)q2 | ((unsigned)q3 << 16));
        ov.z = (int)((unsigned)q4 | ((unsigned)q5 << 16));
        ov.w = (int)((unsigned)q6 | ((unsigned)q7 << 16));
        *reinterpret_cast<int4*>(mbB + (((size_t)ti * 32 + jc) * 64 + lane) * 8) = ov;
        return;
    }

    // ---- h_prime part: MFMA, 32 rows per block, wave = head ----
    const int blk = blockIdx.x - 512;        // 0..255
    const int b   = blk >> 5;                // / (N/32)
    const int n0  = (blk & 31) * 32;

    {   // stage 32 rows x 128 f32 (16.9KB): 1024 float4, 4 per thread
        const float* src = h + ((size_t)b * N + n0) * FIN;
        for (int v = t; v < 1024; v += 256) {
            float4 x = reinterpret_cast<const float4*>(src)[v];
            int fl = v * 4;
            *reinterpret_cast<float4*>(&h_lds[fl >> 7][fl & 127]) = x;
        }
    }

    const int hd   = t >> 6;
    const int lane = t & 63;
    const int li   = lane & 15;
    const int kg   = lane >> 4;

    // Build W B-fragments: wf[ks][ft][e] = bf16(W[hd][ks*32+8kg+e][16ft+li])
    // (L2-hot, read once; 16-lane-consecutive li -> 64B segments)
    short8 wf[4][4];
    {
        const float* Wp = W + (size_t)hd * FIN * FOUT;
        #pragma unroll
        for (int ks = 0; ks < 4; ++ks)
            #pragma unroll
            for (int ft = 0; ft < 4; ++ft) {
                const float* wb = Wp + (size_t)(ks * 32 + 8 * kg) * FOUT + 16 * ft + li;
                int4 pk_;
                float u0 = wb[0],       u1 = wb[64],      u2 = wb[128], u3 = wb[192];
                float u4 = wb[256],     u5 = wb[320],     u6 = wb[384], u7 = wb[448];
                asm("v_cvt_pk_bf16_f32 %0, %1, %2" : "=v"(pk_.x) : "v"(u0), "v"(u1));
                asm("v_cvt_pk_bf16_f32 %0, %1, %2" : "=v"(pk_.y) : "v"(u2), "v"(u3));
                asm("v_cvt_pk_bf16_f32 %0, %1, %2" : "=v"(pk_.z) : "v"(u4), "v"(u5));
                asm("v_cvt_pk_bf16_f32 %0, %1, %2" : "=v"(pk_.w) : "v"(u6), "v"(u7));
                wf[ks][ft] = *reinterpret_cast<short8*>(&pk_);
            }
    }
    __syncthreads();                          // h_lds ready

    f32x4 c[4][2];                            // [ft][rt]
    #pragma unroll
    for (int ft = 0; ft < 4; ++ft)
        #pragma unroll
        for (int rt = 0; rt < 2; ++rt) c[ft][rt] = f32x4{0.f, 0.f, 0.f, 0.f};

    #pragma unroll
    for (int rt = 0; rt < 2; ++rt) {
        #pragma unroll
        for (int ks = 0; ks < 4; ++ks) {
            // A-frag: a[e] = bf16(h_lds[16rt+li][ks*32+8kg+e])
            const float* hp8 = &h_lds[16 * rt + li][ks * 32 + 8 * kg];
            float4 x0 = *reinterpret_cast<const float4*>(hp8);
            float4 x1 = *reinterpret_cast<const float4*>(hp8 + 4);
            int4 pk_;
            asm("v_cvt_pk_bf16_f32 %0, %1, %2" : "=v"(pk_.x) : "v"(x0.x), "v"(x0.y));
            asm("v_cvt_pk_bf16_f32 %0, %1, %2" : "=v"(pk_.y) : "v"(x0.z), "v"(x0.w));
            asm("v_cvt_pk_bf16_f32 %0, %1, %2" : "=v"(pk_.z) : "v"(x1.x), "v"(x1.y));
            asm("v_cvt_pk_bf16_f32 %0, %1, %2" : "=v"(pk_.w) : "v"(x1.z), "v"(x1.w));
            short8 af = *reinterpret_cast<short8*>(&pk_);
            c[0][rt] = __builtin_amdgcn_mfma_f32_16x16x32_bf16(af, wf[ks][0], c[0][rt], 0, 0, 0);
            c[1][rt] = __builtin_amdgcn_mfma_f32_16x16x32_bf16(af, wf[ks][1], c[1][rt], 0, 0, 0);
            c[2][rt] = __builtin_amdgcn_mfma_f32_16x16x32_bf16(af, wf[ks][2], c[2][rt], 0, 0, 0);
            c[3][rt] = __builtin_amdgcn_mfma_f32_16x16x32_bf16(af, wf[ks][3], c[3][rt], 0, 0, 0);
        }
    }

    const int bh = b * H + hd;
    const int jc = n0 >> 5;
    // hpF store: value c[ft][rt][r] = hp[n0+16rt+4kg+r][16ft+li]
    //   -> lanep = li + 16*(2rt+(kg>>1)), e0 = 4*(kg&1)  (audited vs R13 formula)
    #pragma unroll
    for (int ft = 0; ft < 4; ++ft)
        #pragma unroll
        for (int rt = 0; rt < 2; ++rt) {
            short4v v4;
            v4[0] = (short)f2bf(c[ft][rt][0]);
            v4[1] = (short)f2bf(c[ft][rt][1]);
            v4[2] = (short)f2bf(c[ft][rt][2]);
            v4[3] = (short)f2bf(c[ft][rt][3]);
            const int lanep = li + 16 * (2 * rt + (kg >> 1));
            *reinterpret_cast<short4v*>(
                hpF + ((((size_t)bh * 32 + jc) * 4 + ft) * 64 + lanep) * 8 + 4 * (kg & 1)) = v4;
        }

    // ei/ej: e1[n] = sum_f hp[n][f]*a1[f]; per lane holds f = 16ft+li
    float a1v[4], a2v[4];
    #pragma unroll
    for (int ft = 0; ft < 4; ++ft) {
        a1v[ft] = a[(size_t)hd * 2 * FOUT + 16 * ft + li];
        a2v[ft] = a[(size_t)hd * 2 * FOUT + FOUT + 16 * ft + li];
    }
    #pragma unroll
    for (int rt = 0; rt < 2; ++rt)
        #pragma unroll
        for (int r = 0; r < 4; ++r) {
            float e1 = c[0][rt][r] * a1v[0] + c[1][rt][r] * a1v[1]
                     + c[2][rt][r] * a1v[2] + c[3][rt][r] * a1v[3];
            float e2 = c[0][rt][r] * a2v[0] + c[1][rt][r] * a2v[1]
                     + c[2][rt][r] * a2v[2] + c[3][rt][r] * a2v[3];
            #pragma unroll
            for (int m = 1; m < 16; m <<= 1) {
                e1 += __shfl_xor(e1, m, 64);
                e2 += __shfl_xor(e2, m, 64);
            }
            if (li == 0) {                    // lanes 0,16,32,48: rows of their kg
                int rr = n0 + 16 * rt + 4 * kg + r;
                ei_t[(size_t)bh * N + rr] = LOG2E * e1;
                ej_t[(size_t)bh * N + rr] = LOG2E * e2;
            }
        }
}

// ---------------------------------------------------------------------------
// Kernel B: fused scores+softmax+PV — R17-verified VERBATIM (35.2µs).
// ---------------------------------------------------------------------------
__global__ __launch_bounds__(512) void gat_attn(
    const unsigned short* __restrict__ hpF, // fragment-order bf16
    const float* __restrict__ ei_t,         // (B,H,N) *LOG2E
    const float* __restrict__ ej_t,         // (B,H,N) *LOG2E
    const unsigned short* __restrict__ mbB, // fragment-order bf16 masked bias
    float* __restrict__ out)                // (B,N,H*FOUT)
{
    __shared__ __align__(16) char smem[32768];   // hstage[4] x 8KB; red (20KB) aliased after loop
    typedef unsigned short hstage_t[2][4][512];
    hstage_t* hstage = reinterpret_cast<hstage_t*>(smem);

    const int raw  = blockIdx.x;            // 512
    const int xcd  = raw & 7;
    const int k_   = raw >> 3;
    const int bh   = ((xcd >> 1) << 3) | (k_ >> 3);          // 8 bh per XCD
    const int it0  = (((xcd & 1) << 3) | (k_ & 7)) * 4;      // 4 i-tiles/block
    const int t    = threadIdx.x;
    const int w8   = t >> 6;
    const int w    = w8 & 3;                // i-tile (also f-tile staged)
    const int jh   = w8 >> 2;               // j-half
    const int lane = t & 63;
    const int li   = lane & 15;
    const int kg   = lane >> 4;
    const int ti   = it0 + w;
    const int irow = ti * 16 + li;
    const int jcb  = jh * 16;               // first chunk of this wave's half

    const float  ei0   = ei_t[(size_t)bh * N + irow];
    const float* ejrow = ej_t + (size_t)bh * N;
    const unsigned short* mrow = mbB + ((size_t)ti * 32 * 64 + lane) * 8;  // + jc*512
    const size_t hbase = (size_t)bh * 65536;                               // u16/slab

    f32x4 c0 = {0.f,0.f,0.f,0.f}, c1 = {0.f,0.f,0.f,0.f};
    f32x4 c2 = {0.f,0.f,0.f,0.f}, c3 = {0.f,0.f,0.f,0.f};
    f32x4 c4 = {0.f,0.f,0.f,0.f};
    const short obf = (short)0x3F80;                      // bf16 1.0
    const short8 ones = {obf,obf,obf,obf,obf,obf,obf,obf};

    #define VMCNT6() asm volatile("s_waitcnt vmcnt(6)" ::: "memory")
    #define BARRIER() { __builtin_amdgcn_s_barrier(); asm volatile("" ::: "memory"); }

    // stage f-tile w of chunk JCG into hstage[BUF][jh][w]
    #define STAGE(BUF, JCG) {                                                 \
        const unsigned short* gs_ = hpF + hbase + (size_t)(JCG) * 2048        \
                                        + (size_t)w * 512 + (size_t)lane * 8; \
        __builtin_amdgcn_global_load_lds(                                     \
            (const __attribute__((address_space(1))) void*)gs_,               \
            (__attribute__((address_space(3))) void*)&hstage[BUF][jh][w][0],  \
            16, 0, 0); }

    // register prefetch for chunk JCG into set S (mq + 2 ej float4s)
    #define REGS(S, JCG) {                                                    \
        mq##S  = *reinterpret_cast<const int4*>(mrow + (size_t)(JCG) * 512);  \
        ejA##S = *reinterpret_cast<const float4*>(ejrow + (JCG) * 32 + 8 * kg);\
        ejB##S = *reinterpret_cast<const float4*>(ejrow + (JCG) * 32 + 8 * kg + 4); }

    #define DSREAD(BUF, BA, BB, BC, BD) {                                     \
        BA = *reinterpret_cast<const short8*>(&hstage[BUF][jh][0][lane * 8]); \
        BB = *reinterpret_cast<const short8*>(&hstage[BUF][jh][1][lane * 8]); \
        BC = *reinterpret_cast<const short8*>(&hstage[BUF][jh][2][lane * 8]); \
        BD = *reinterpret_cast<const short8*>(&hstage[BUF][jh][3][lane * 8]); }

    // two scores from one packed-bf16 word (lo = even elem, hi = odd elem)
    #define SCORE2(PL, PH, EJL, EJH, QW) {                                    \
        float bl_ = __uint_as_float(((unsigned)(QW)) << 16);                  \
        float bh_ = __uint_as_float(((unsigned)(QW)) & 0xffff0000u);          \
        float el_ = ei0 + (EJL); el_ = fmaxf(el_, 0.2f * el_) + bl_;          \
        float eh_ = ei0 + (EJH); eh_ = fmaxf(eh_, 0.2f * eh_) + bh_;          \
        asm("v_exp_f32 %0, %1" : "=v"(PL) : "v"(el_));                        \
        asm("v_exp_f32 %0, %1" : "=v"(PH) : "v"(eh_)); }

    #define COMPS(S, BA, BB, BC, BD) {                                        \
        float p0,p1,p2,p3,p4,p5,p6,p7;                                        \
        SCORE2(p0, p1, ejA##S.x, ejA##S.y, mq##S.x)                           \
        SCORE2(p2, p3, ejA##S.z, ejA##S.w, mq##S.y)                           \
        SCORE2(p4, p5, ejB##S.x, ejB##S.y, mq##S.z)                           \
        SCORE2(p6, p7, ejB##S.z, ejB##S.w, mq##S.w)                           \
        int4 pk_;                                                             \
        asm("v_cvt_pk_bf16_f32 %0, %1, %2" : "=v"(pk_.x) : "v"(p0), "v"(p1)); \
        asm("v_cvt_pk_bf16_f32 %0, %1, %2" : "=v"(pk_.y) : "v"(p2), "v"(p3)); \
        asm("v_cvt_pk_bf16_f32 %0, %1, %2" : "=v"(pk_.z) : "v"(p4), "v"(p5)); \
        asm("v_cvt_pk_bf16_f32 %0, %1, %2" : "=v"(pk_.w) : "v"(p6), "v"(p7)); \
        short8 a0_ = *reinterpret_cast<short8*>(&pk_);                        \
        c0 = __builtin_amdgcn_mfma_f32_16x16x32_bf16(a0_, BA, c0, 0, 0, 0);   \
        c1 = __builtin_amdgcn_mfma_f32_16x16x32_bf16(a0_, BB, c1, 0, 0, 0);   \
        c2 = __builtin_amdgcn_mfma_f32_16x16x32_bf16(a0_, BC, c2, 0, 0, 0);   \
        c3 = __builtin_amdgcn_mfma_f32_16x16x32_bf16(a0_, BD, c3, 0, 0, 0);   \
        c4 = __builtin_amdgcn_mfma_f32_16x16x32_bf16(a0_, ones, c4, 0, 0, 0); }

    short8 A0, B0, C0, D0, A1, B1, C1, D1;
    int4 mq0, mq1;
    float4 ejA0, ejB0, ejA1, ejB1;

    // prologue: stage chunks 0,1 (buf 0,1); regs for chunks 0,1.
    STAGE(0, jcb + 0)
    STAGE(1, jcb + 1)
    REGS(0, jcb + 0)
    REGS(1, jcb + 1)
    VMCNT6();                                // both STAGEs retired
    BARRIER();

    // 8 merged phases; phase k consumes chunks k,k+1 from bufs k%4,(k+1)%4
    // and stages chunks k+2,k+3 into bufs (k+2)%4,(k+3)%4.
    #pragma unroll 1
    for (int k = 0; k < 16; k += 2) {
        const int pa = (k + 2 < 16) ? jcb + k + 2 : jcb + 15;   // clamped prefetch
        const int pb = (k + 3 < 16) ? jcb + k + 3 : jcb + 15;
        const int ba = k & 2 ? 2 : 0;        // k%4 (k even)
        const int bb = ba + 1;               // (k+1)%4
        const int bn0 = ba ^ 2;              // (k+2)%4
        const int bn1 = bb ^ 2;              // (k+3)%4
        // issue next-phase stages up front
        STAGE(bn0, pa)
        STAGE(bn1, pb)
        // consume chunk k
        DSREAD(ba, A0, B0, C0, D0)
        COMPS(0, A0, B0, C0, D0)
        REGS(0, pa)
        // consume chunk k+1
        DSREAD(bb, A1, B1, C1, D1)
        COMPS(1, A1, B1, C1, D1)
        REGS(1, pb)
        VMCNT6();                            // retires this phase's 2 STAGEs (oldest)
        BARRIER();
    }
    #undef VMCNT6
    #undef BARRIER
    #undef STAGE
    #undef REGS
    #undef DSREAD
    #undef SCORE2
    #undef COMPS

    // hstage is dead from here on: alias the reduce buffer over it
    f32x4 (*red)[4][64] = reinterpret_cast<f32x4 (*)[4][64]>(smem);

    __syncthreads();                         // everyone past final DSREAD
    if (jh == 1) {
        red[0][w][lane] = c0;
        red[1][w][lane] = c1;
        red[2][w][lane] = c2;
        red[3][w][lane] = c3;
        red[4][w][lane] = c4;
    }
    __syncthreads();
    if (jh == 1) return;

    c0 += red[0][w][lane];
    c1 += red[1][w][lane];
    c2 += red[2][w][lane];
    c3 += red[3][w][lane];
    c4 += red[4][w][lane];

    // C layout col=li (f within tile), row=4*kg+r; c4[r] = that row's sum.
    const int b  = bh >> 2;
    const int hd = bh & 3;
    #pragma unroll
    for (int r = 0; r < 4; ++r) {
        int orow = ti * 16 + 4 * kg + r;
        float inv = 1.0f / c4[r];
        float* ob = out + (((size_t)b * N + orow) * H + hd) * 64 + li;
        ob[0]  = c0[r] * inv;
        ob[16] = c1[r] * inv;
        ob[32] = c2[r] * inv;
        ob[48] = c3[r] * inv;
    }
}

extern "C" void kernel_launch(void* const* d_in, const int* in_sizes, int n_in,
                              void* d_out, int out_size, void* d_ws, size_t ws_size,
                              hipStream_t stream) {
    const float* h    = (const float*)d_in[0];
    const int*   adj  = (const int*)  d_in[1];
    const float* bias = (const float*)d_in[2];
    const float* W    = (const float*)d_in[3];
    const float* a    = (const float*)d_in[4];
    float* out = (float*)d_out;

    char* ws = (char*)d_ws;
    unsigned short* hpF = (unsigned short*)ws;                        // 4 MB
    unsigned short* mbB = (unsigned short*)(ws + ((size_t)4 << 20));  // 2 MB
    float* ei_t = (float*)(ws + ((size_t)6 << 20));                   // 128 KB
    float* ej_t = ei_t + (size_t)B * H * N;                           // 128 KB

    gat_prep<<<512 + B * N / 32, 256, 0, stream>>>(h, W, a, adj, bias,
                                                   hpF, mbB, ei_t, ej_t);
    gat_attn<<<B * H * (N / 64), 512, 0, stream>>>(hpF, ei_t, ej_t, mbB, out);
}